// Round 7
// baseline (329.623 us; speedup 1.0000x reference)
//
#include <hip/hip_runtime.h>

#define T_TOKENS 8192
#define D_MODEL  4096
#define N_EXP    64
#define BT       256          // tokens per gemm block
#define TAU      4e-6f        // gap threshold for f64 repair (~285 sigma of f32 err)

#define GLB(p)  ((const __attribute__((address_space(1))) void*)(p))
#define LDSP(p) ((__attribute__((address_space(3))) void*)(p))

// ---------------------------------------------------------------------------
// Kernel 1: f32 partial GEMM, 2-phase double-buffered, BK=32 (R5 tile params).
// part[ks][t][e] = sum_{k in slice} h[t][k]*w[e][k]
// grid (32, KS), block 256 (4 waves). Tile 256 tokens x 64 experts.
// Per 32-k tile: STAGE(next buf) -> compute(cur buf) -> one barrier.
// Stagger (lane&15)*2 over 32-float rows = R5's proven conflict-free pattern.
// LDS 80 KB -> 2 blocks/CU; prefetch covers load latency under compute.
// ---------------------------------------------------------------------------
__global__ __launch_bounds__(256) void k_gemm(const float* __restrict__ h,
                                              const float* __restrict__ w,
                                              float* __restrict__ part,
                                              int ks_len) {
    __shared__ float lh0[BT][32], lh1[BT][32];       // 32 KB x 2
    __shared__ float lw0[N_EXP][32], lw1[N_EXP][32]; //  8 KB x 2  => 80 KB
    const int tid  = threadIdx.x;
    const int wv   = tid >> 6;       // wave 0..3
    const int lane = tid & 63;
    const int T0   = blockIdx.x * BT;
    const int k0   = blockIdx.y * ks_len;

    const int tloc = wv * 64 + (lane & 7) * 8;  // 8 consecutive tokens
    const int eloc = (lane >> 3) * 8;           // 8 consecutive experts
    const int ko   = (lane & 15) * 2;           // even k-stagger offset (R5)

    float acc[8][8];
#pragma unroll
    for (int i = 0; i < 8; ++i)
#pragma unroll
        for (int j = 0; j < 8; ++j) acc[i][j] = 0.f;

    auto stage = [&](float (&LH)[BT][32], float (&LW)[N_EXP][32], int kb) {
#pragma unroll
        for (int q = 0; q < 8; ++q) {
            const int trow = wv * 64 + q * 8;   // wave-uniform LDS base
            const float* g = &h[(size_t)(T0 + trow + (lane >> 3)) * D_MODEL
                                + kb + (lane & 7) * 4];
            __builtin_amdgcn_global_load_lds(GLB(g), LDSP(&LH[trow][0]), 16, 0, 0);
        }
#pragma unroll
        for (int q = 0; q < 2; ++q) {
            const int erow = wv * 16 + q * 8;   // wave-uniform LDS base
            const float* g = &w[(size_t)(erow + (lane >> 3)) * D_MODEL
                                + kb + (lane & 7) * 4];
            __builtin_amdgcn_global_load_lds(GLB(g), LDSP(&LW[erow][0]), 16, 0, 0);
        }
    };

    auto compute = [&](float (&LH)[BT][32], float (&LW)[N_EXP][32]) {
#pragma unroll
        for (int u = 0; u < 16; ++u) {
            const int kk = (2 * u + ko) & 31;   // per-lane staggered k (even)
            float2 hv[8], wv2[8];
#pragma unroll
            for (int i = 0; i < 8; ++i)
                hv[i] = *reinterpret_cast<const float2*>(&LH[tloc + i][kk]);
#pragma unroll
            for (int j = 0; j < 8; ++j)
                wv2[j] = *reinterpret_cast<const float2*>(&LW[eloc + j][kk]);
#pragma unroll
            for (int i = 0; i < 8; ++i)
#pragma unroll
                for (int j = 0; j < 8; ++j) {
                    acc[i][j] = fmaf(hv[i].x, wv2[j].x, acc[i][j]);
                    acc[i][j] = fmaf(hv[i].y, wv2[j].y, acc[i][j]);
                }
        }
    };

    const int iters = ks_len >> 5;  // 32-k tiles; 8 at KS=16 (even)
    stage(lh0, lw0, k0);
    __syncthreads();                // prologue drain
    for (int it = 0; it < iters; it += 2) {
        if (it + 1 < iters) stage(lh1, lw1, k0 + (it + 1) * 32);
        compute(lh0, lw0);
        __syncthreads();            // b1 loads landed during compute; b0 free
        if (it + 2 < iters) stage(lh0, lw0, k0 + (it + 2) * 32);
        compute(lh1, lw1);
        __syncthreads();
    }

    float* base = part + ((size_t)blockIdx.y * T_TOKENS + T0) * N_EXP;
#pragma unroll
    for (int i = 0; i < 8; ++i) {
        const int t = tloc + i;
        const float4 o0 = make_float4(acc[i][0], acc[i][1], acc[i][2], acc[i][3]);
        const float4 o1 = make_float4(acc[i][4], acc[i][5], acc[i][6], acc[i][7]);
        *reinterpret_cast<float4*>(&base[(size_t)t * N_EXP + eloc])     = o0;
        *reinterpret_cast<float4*>(&base[(size_t)t * N_EXP + eloc + 4]) = o1;
    }
}

// ---------------------------------------------------------------------------
// Kernel 2: per-token softmax + top-8 + gap-based tie flagging + aux partials.
// block 256 (4 waves), wave handles 4 tokens, lane = expert. f32 throughout.
// ---------------------------------------------------------------------------
__global__ __launch_bounds__(256) void k_router(const float* __restrict__ part, int KS,
                                                float* __restrict__ out_idx,
                                                float* __restrict__ out_w,
                                                float* __restrict__ expsum,
                                                int* __restrict__ flag_cnt,
                                                int* __restrict__ flag_list) {
    __shared__ float laux[4][64];
    const int lane = threadIdx.x & 63;
    const int wid  = threadIdx.x >> 6;
    float aux_acc = 0.f;
    const int tbase = blockIdx.x * 16 + wid * 4;
    const size_t kstride = (size_t)T_TOKENS * N_EXP;

    for (int tt = 0; tt < 4; ++tt) {
        const int t = tbase + tt;
        const float* pb = part + (size_t)t * N_EXP + lane;
        float a0 = 0.f, a1 = 0.f, a2 = 0.f, a3 = 0.f;
        int ksi = 0;
        for (; ksi + 4 <= KS; ksi += 4) {
            a0 += pb[(size_t)(ksi + 0) * kstride];
            a1 += pb[(size_t)(ksi + 1) * kstride];
            a2 += pb[(size_t)(ksi + 2) * kstride];
            a3 += pb[(size_t)(ksi + 3) * kstride];
        }
        for (; ksi < KS; ++ksi) a0 += pb[(size_t)ksi * kstride];
        const float lg = (a0 + a1) + (a2 + a3);

        float m = lg;
#pragma unroll
        for (int off = 32; off; off >>= 1) m = fmaxf(m, __shfl_xor(m, off));
        const float p = __expf(lg - m);
        float s = p;
#pragma unroll
        for (int off = 32; off; off >>= 1) s += __shfl_xor(s, off);
        const float inv_s = 1.f / s;
        aux_acc += p * inv_s;

        // top-9 rounds: select top-8, measure all 9 adjacent gaps
        float pv = lg; int pi = lane;
        float myp = 0.f; int myi = 0; float tsum = 0.f, prev = 0.f;
        bool flg = false;
#pragma unroll
        for (int r = 0; r < 9; ++r) {
            float bv = pv; int bi = pi;
#pragma unroll
            for (int off = 32; off; off >>= 1) {
                const float ov = __shfl_xor(bv, off);
                const int   oi = __shfl_xor(bi, off);
                if (ov > bv || (ov == bv && oi < bi)) { bv = ov; bi = oi; }
            }
            if (r > 0) flg = flg || (prev - bv < TAU);
            prev = bv;
            if (r < 8) {
                const float bp = __expf(bv - m) * inv_s;
                tsum += bp;
                if (lane == r)  { myp = bp; myi = bi; }
                if (lane == bi) pv = -1e30f;
            }
        }
        if (lane < 8) {
            out_idx[(size_t)t * 8 + lane] = (float)myi;
            out_w[(size_t)t * 8 + lane]   = myp / tsum;
        }
        if (lane == 0 && flg) {
            const int pos = atomicAdd(flag_cnt, 1);
            if (pos < T_TOKENS) flag_list[pos] = t;
        }
    }

    laux[wid][lane] = aux_acc;
    __syncthreads();
    if (threadIdx.x < 64)
        expsum[(size_t)blockIdx.x * 64 + threadIdx.x] =
            laux[0][threadIdx.x] + laux[1][threadIdx.x] +
            laux[2][threadIdx.x] + laux[3][threadIdx.x];
}

// ---------------------------------------------------------------------------
// Kernel 3: f64 repair, one block per flagged token. lane = expert, wave = k
// chunk. Inner loop unrolled 8x (16 loads in flight, 8 independent f64 acc).
// ---------------------------------------------------------------------------
__global__ __launch_bounds__(256) void k_repair(const float* __restrict__ h,
                                                const float* __restrict__ w,
                                                const int* __restrict__ flag_cnt,
                                                const int* __restrict__ flag_list,
                                                float* __restrict__ out_idx,
                                                float* __restrict__ out_w) {
    __shared__ float  sh[D_MODEL];   // 16 KB
    __shared__ double sp[4][64];     //  2 KB
    const int tid  = threadIdx.x;
    const int lane = tid & 63;
    const int c    = tid >> 6;       // k-chunk = wave id
    const int n = min(*flag_cnt, T_TOKENS);

    for (int i = blockIdx.x; i < n; i += gridDim.x) {
        const int t = flag_list[i];
        __syncthreads();   // previous iteration's readers done
#pragma unroll
        for (int q = 0; q < 4; ++q) {
            const int o = (q * 256 + tid) * 4;
            *reinterpret_cast<float4*>(&sh[o]) =
                *reinterpret_cast<const float4*>(&h[(size_t)t * D_MODEL + o]);
        }
        __syncthreads();

        const float* wp = &w[(size_t)lane * D_MODEL + c * 1024];
        const float* hp = &sh[c * 1024];
        double acc[8] = {0, 0, 0, 0, 0, 0, 0, 0};
        for (int q = 0; q < 32; ++q) {          // 32 chunks x 8 float4
            float4 wv8[8], hv8[8];
#pragma unroll
            for (int u = 0; u < 8; ++u) {
                wv8[u] = *reinterpret_cast<const float4*>(&wp[(q * 8 + u) * 4]);
                hv8[u] = *reinterpret_cast<const float4*>(&hp[(q * 8 + u) * 4]);
            }
#pragma unroll
            for (int u = 0; u < 8; ++u) {
                acc[u] = fma((double)hv8[u].x, (double)wv8[u].x, acc[u]);
                acc[u] = fma((double)hv8[u].y, (double)wv8[u].y, acc[u]);
                acc[u] = fma((double)hv8[u].z, (double)wv8[u].z, acc[u]);
                acc[u] = fma((double)hv8[u].w, (double)wv8[u].w, acc[u]);
            }
        }
        sp[c][lane] = (((acc[0] + acc[1]) + (acc[2] + acc[3])) +
                       ((acc[4] + acc[5]) + (acc[6] + acc[7])));
        __syncthreads();

        if (tid < 64) {
            const double mylg = ((sp[0][lane] + sp[1][lane]) +
                                 (sp[2][lane] + sp[3][lane]));
            double m = mylg;
#pragma unroll
            for (int off = 32; off; off >>= 1) m = fmax(m, __shfl_xor(m, off));
            double pv = mylg; int pi = lane;
            double myp = 0.0; int myi = 0; double tsum = 0.0;
#pragma unroll
            for (int r = 0; r < 8; ++r) {
                double bv = pv; int bi = pi;
#pragma unroll
                for (int off = 32; off; off >>= 1) {
                    const double ov = __shfl_xor(bv, off);
                    const int    oi = __shfl_xor(bi, off);
                    if (ov > bv || (ov == bv && oi < bi)) { bv = ov; bi = oi; }
                }
                const double bp = exp(bv - m);
                tsum += bp;
                if (lane == r)  { myp = bp; myi = bi; }
                if (lane == bi) pv = -1.0e300;
            }
            if (lane < 8) {
                out_idx[(size_t)t * 8 + lane] = (float)myi;
                out_w[(size_t)t * 8 + lane]   = (float)(myp / tsum);
            }
        }
    }
}

// ---------------------------------------------------------------------------
// Kernel 4: aux loss finalize. 1 block, 256 threads (4 slices x 64 experts).
// ---------------------------------------------------------------------------
__global__ __launch_bounds__(256) void k_aux(const float* __restrict__ expsum, int nb,
                                             float* __restrict__ out_aux) {
    __shared__ float l[4][64];
    const int lane  = threadIdx.x & 63;
    const int slice = threadIdx.x >> 6;
    float s = 0.f;
    for (int b = slice; b < nb; b += 4) s += expsum[(size_t)b * 64 + lane];
    l[slice][lane] = s;
    __syncthreads();
    if (threadIdx.x < 64) {
        const float tot = l[0][lane] + l[1][lane] + l[2][lane] + l[3][lane];
        const float avg = tot * (1.f / (float)T_TOKENS);
        float v = avg * avg;
#pragma unroll
        for (int off = 32; off; off >>= 1) v += __shfl_xor(v, off);
        if (lane == 0) out_aux[0] = (float)N_EXP * 0.001f * v;
    }
}

extern "C" void kernel_launch(void* const* d_in, const int* in_sizes, int n_in,
                              void* d_out, int out_size, void* d_ws, size_t ws_size,
                              hipStream_t stream) {
    const float* h = (const float*)d_in[0];   // [8192,4096]
    const float* w = (const float*)d_in[1];   // [64,4096]
    float* out      = (float*)d_out;
    float* out_idx  = out;                    // 65536 (indices as float)
    float* out_w    = out + 65536;            // 65536
    float* out_aux  = out + 131072;           // 1

    const size_t part_elems = (size_t)T_TOKENS * N_EXP;
    const int NB2 = 512;
    int KS = 16;                              // 512 blocks = 2/CU, 32 MB part
    while (KS > 1 &&
           ((size_t)KS * part_elems * 4 + (size_t)NB2 * 64 * 4 +
            4 + (size_t)T_TOKENS * 4) > ws_size)
        KS >>= 1;

    float* part     = (float*)d_ws;
    float* expsum   = part + (size_t)KS * part_elems;
    int*   flag_cnt = (int*)(expsum + (size_t)NB2 * 64);
    int*   flag_list= flag_cnt + 1;

    hipMemsetAsync(flag_cnt, 0, sizeof(int), stream);

    dim3 g1(T_TOKENS / BT, KS);
    k_gemm<<<g1, 256, 0, stream>>>(h, w, part, D_MODEL / KS);
    k_router<<<NB2, 256, 0, stream>>>(part, KS, out_idx, out_w, expsum,
                                      flag_cnt, flag_list);
    k_repair<<<512, 256, 0, stream>>>(h, w, flag_cnt, flag_list, out_idx, out_w);
    k_aux<<<1, 256, 0, stream>>>(expsum, NB2, out_aux);
}

// Round 8
// 169.914 us; speedup vs baseline: 1.9399x; 1.9399x over previous
//
#include <hip/hip_runtime.h>

#define T_TOKENS 8192
#define D_MODEL  4096
#define N_EXP    64
#define BT       256          // tokens per gemm block
#define TAU      4e-6f        // gap threshold for f64 repair (~285 sigma of f32 err)

#define GLB(p)  ((const __attribute__((address_space(1))) void*)(p))
#define LDSP(p) ((__attribute__((address_space(3))) void*)(p))

// ---------------------------------------------------------------------------
// Kernel 1: f32 partial GEMM, 2-phase double-buffered, BK=32, SINGLE compute
// body (runtime buffer index -> no duplicated unrolled bodies -> no VGPR
// explosion like R6/R7). Schedule per 32-k tile:
//   stage(next buf) ; compute(cur buf) ; __syncthreads()
// Next-tile global_load_lds always has the full compute phase to land, so the
// barrier's implicit vmcnt(0) drain is ~free. One barrier per tile.
// Stagger (lane&15)*2 over 32-float rows = R5's proven conflict-free pattern.
// ---------------------------------------------------------------------------
__global__ __launch_bounds__(256) void k_gemm(const float* __restrict__ h,
                                              const float* __restrict__ w,
                                              float* __restrict__ part,
                                              int ks_len) {
    __shared__ float lh[2][BT][32];     // 64 KB
    __shared__ float lw[2][N_EXP][32];  // 16 KB  => 80 KB total, 2 blocks/CU
    const int tid  = threadIdx.x;
    const int wv   = tid >> 6;       // wave 0..3
    const int lane = tid & 63;
    const int T0   = blockIdx.x * BT;
    const int k0   = blockIdx.y * ks_len;

    const int tloc = wv * 64 + (lane & 7) * 8;  // 8 consecutive tokens
    const int eloc = (lane >> 3) * 8;           // 8 consecutive experts
    const int ko   = (lane & 15) * 2;           // even k-stagger offset

    // per-thread global staging bases (advance by it*32 floats per tile)
    const float* ghb = h + (size_t)(T0 + wv * 64 + (lane >> 3)) * D_MODEL
                         + k0 + (lane & 7) * 4;
    const float* gwb = w + (size_t)(wv * 16 + (lane >> 3)) * D_MODEL
                         + k0 + (lane & 7) * 4;

    float acc[8][8];
#pragma unroll
    for (int i = 0; i < 8; ++i)
#pragma unroll
        for (int j = 0; j < 8; ++j) acc[i][j] = 0.f;

    auto stage = [&](int b, int it) {
#pragma unroll
        for (int q = 0; q < 8; ++q)
            __builtin_amdgcn_global_load_lds(
                GLB(ghb + it * 32 + (size_t)q * 8 * D_MODEL),
                LDSP(&lh[b][wv * 64 + q * 8][0]), 16, 0, 0);
#pragma unroll
        for (int q = 0; q < 2; ++q)
            __builtin_amdgcn_global_load_lds(
                GLB(gwb + it * 32 + (size_t)q * 8 * D_MODEL),
                LDSP(&lw[b][wv * 16 + q * 8][0]), 16, 0, 0);
    };

    const int iters = ks_len >> 5;      // 8 tiles at KS=16
    stage(0, 0);
    __syncthreads();                    // prologue drain (exposed once)
    for (int it = 0; it < iters; ++it) {
        const int b = it & 1;
        if (it + 1 < iters) stage(b ^ 1, it + 1);   // lands during compute
#pragma unroll
        for (int u = 0; u < 16; ++u) {
            const int kk = (2 * u + ko) & 31;       // staggered k (even)
            float2 hv[8], wv2[8];
#pragma unroll
            for (int i = 0; i < 8; ++i)
                hv[i] = *reinterpret_cast<const float2*>(&lh[b][tloc + i][kk]);
#pragma unroll
            for (int j = 0; j < 8; ++j)
                wv2[j] = *reinterpret_cast<const float2*>(&lw[b][eloc + j][kk]);
#pragma unroll
            for (int i = 0; i < 8; ++i)
#pragma unroll
                for (int j = 0; j < 8; ++j) {
                    acc[i][j] = fmaf(hv[i].x, wv2[j].x, acc[i][j]);
                    acc[i][j] = fmaf(hv[i].y, wv2[j].y, acc[i][j]);
                }
        }
        __syncthreads();   // next-buf writes visible; cur readers done
    }

    float* base = part + ((size_t)blockIdx.y * T_TOKENS + T0) * N_EXP;
#pragma unroll
    for (int i = 0; i < 8; ++i) {
        const int t = tloc + i;
        const float4 o0 = make_float4(acc[i][0], acc[i][1], acc[i][2], acc[i][3]);
        const float4 o1 = make_float4(acc[i][4], acc[i][5], acc[i][6], acc[i][7]);
        *reinterpret_cast<float4*>(&base[(size_t)t * N_EXP + eloc])     = o0;
        *reinterpret_cast<float4*>(&base[(size_t)t * N_EXP + eloc + 4]) = o1;
    }
}

// ---------------------------------------------------------------------------
// Kernel 2: per-token softmax + top-8 + gap-based tie flagging + aux partials.
// block 256 (4 waves), wave handles 4 tokens, lane = expert. f32 throughout.
// ---------------------------------------------------------------------------
__global__ __launch_bounds__(256) void k_router(const float* __restrict__ part, int KS,
                                                float* __restrict__ out_idx,
                                                float* __restrict__ out_w,
                                                float* __restrict__ expsum,
                                                int* __restrict__ flag_cnt,
                                                int* __restrict__ flag_list) {
    __shared__ float laux[4][64];
    const int lane = threadIdx.x & 63;
    const int wid  = threadIdx.x >> 6;
    float aux_acc = 0.f;
    const int tbase = blockIdx.x * 16 + wid * 4;
    const size_t kstride = (size_t)T_TOKENS * N_EXP;

    for (int tt = 0; tt < 4; ++tt) {
        const int t = tbase + tt;
        const float* pb = part + (size_t)t * N_EXP + lane;
        float a0 = 0.f, a1 = 0.f, a2 = 0.f, a3 = 0.f;
        int ksi = 0;
        for (; ksi + 4 <= KS; ksi += 4) {
            a0 += pb[(size_t)(ksi + 0) * kstride];
            a1 += pb[(size_t)(ksi + 1) * kstride];
            a2 += pb[(size_t)(ksi + 2) * kstride];
            a3 += pb[(size_t)(ksi + 3) * kstride];
        }
        for (; ksi < KS; ++ksi) a0 += pb[(size_t)ksi * kstride];
        const float lg = (a0 + a1) + (a2 + a3);

        float m = lg;
#pragma unroll
        for (int off = 32; off; off >>= 1) m = fmaxf(m, __shfl_xor(m, off));
        const float p = __expf(lg - m);
        float s = p;
#pragma unroll
        for (int off = 32; off; off >>= 1) s += __shfl_xor(s, off);
        const float inv_s = 1.f / s;
        aux_acc += p * inv_s;

        // top-9 rounds: select top-8, measure all 9 adjacent gaps
        float pv = lg; int pi = lane;
        float myp = 0.f; int myi = 0; float tsum = 0.f, prev = 0.f;
        bool flg = false;
#pragma unroll
        for (int r = 0; r < 9; ++r) {
            float bv = pv; int bi = pi;
#pragma unroll
            for (int off = 32; off; off >>= 1) {
                const float ov = __shfl_xor(bv, off);
                const int   oi = __shfl_xor(bi, off);
                if (ov > bv || (ov == bv && oi < bi)) { bv = ov; bi = oi; }
            }
            if (r > 0) flg = flg || (prev - bv < TAU);
            prev = bv;
            if (r < 8) {
                const float bp = __expf(bv - m) * inv_s;
                tsum += bp;
                if (lane == r)  { myp = bp; myi = bi; }
                if (lane == bi) pv = -1e30f;
            }
        }
        if (lane < 8) {
            out_idx[(size_t)t * 8 + lane] = (float)myi;
            out_w[(size_t)t * 8 + lane]   = myp / tsum;
        }
        if (lane == 0 && flg) {
            const int pos = atomicAdd(flag_cnt, 1);
            if (pos < T_TOKENS) flag_list[pos] = t;
        }
    }

    laux[wid][lane] = aux_acc;
    __syncthreads();
    if (threadIdx.x < 64)
        expsum[(size_t)blockIdx.x * 64 + threadIdx.x] =
            laux[0][threadIdx.x] + laux[1][threadIdx.x] +
            laux[2][threadIdx.x] + laux[3][threadIdx.x];
}

// ---------------------------------------------------------------------------
// Kernel 3: f64 repair, one block per flagged token. lane = expert, wave = k
// chunk. Inner loop unrolled 8x (16 loads in flight, 8 independent f64 acc).
// ---------------------------------------------------------------------------
__global__ __launch_bounds__(256) void k_repair(const float* __restrict__ h,
                                                const float* __restrict__ w,
                                                const int* __restrict__ flag_cnt,
                                                const int* __restrict__ flag_list,
                                                float* __restrict__ out_idx,
                                                float* __restrict__ out_w) {
    __shared__ float  sh[D_MODEL];   // 16 KB
    __shared__ double sp[4][64];     //  2 KB
    const int tid  = threadIdx.x;
    const int lane = tid & 63;
    const int c    = tid >> 6;       // k-chunk = wave id
    const int n = min(*flag_cnt, T_TOKENS);

    for (int i = blockIdx.x; i < n; i += gridDim.x) {
        const int t = flag_list[i];
        __syncthreads();   // previous iteration's readers done
#pragma unroll
        for (int q = 0; q < 4; ++q) {
            const int o = (q * 256 + tid) * 4;
            *reinterpret_cast<float4*>(&sh[o]) =
                *reinterpret_cast<const float4*>(&h[(size_t)t * D_MODEL + o]);
        }
        __syncthreads();

        const float* wp = &w[(size_t)lane * D_MODEL + c * 1024];
        const float* hp = &sh[c * 1024];
        double acc[8] = {0, 0, 0, 0, 0, 0, 0, 0};
        for (int q = 0; q < 32; ++q) {          // 32 chunks x 8 float4
            float4 wv8[8], hv8[8];
#pragma unroll
            for (int u = 0; u < 8; ++u) {
                wv8[u] = *reinterpret_cast<const float4*>(&wp[(q * 8 + u) * 4]);
                hv8[u] = *reinterpret_cast<const float4*>(&hp[(q * 8 + u) * 4]);
            }
#pragma unroll
            for (int u = 0; u < 8; ++u) {
                acc[u] = fma((double)hv8[u].x, (double)wv8[u].x, acc[u]);
                acc[u] = fma((double)hv8[u].y, (double)wv8[u].y, acc[u]);
                acc[u] = fma((double)hv8[u].z, (double)wv8[u].z, acc[u]);
                acc[u] = fma((double)hv8[u].w, (double)wv8[u].w, acc[u]);
            }
        }
        sp[c][lane] = (((acc[0] + acc[1]) + (acc[2] + acc[3])) +
                       ((acc[4] + acc[5]) + (acc[6] + acc[7])));
        __syncthreads();

        if (tid < 64) {
            const double mylg = ((sp[0][lane] + sp[1][lane]) +
                                 (sp[2][lane] + sp[3][lane]));
            double m = mylg;
#pragma unroll
            for (int off = 32; off; off >>= 1) m = fmax(m, __shfl_xor(m, off));
            double pv = mylg; int pi = lane;
            double myp = 0.0; int myi = 0; double tsum = 0.0;
#pragma unroll
            for (int r = 0; r < 8; ++r) {
                double bv = pv; int bi = pi;
#pragma unroll
                for (int off = 32; off; off >>= 1) {
                    const double ov = __shfl_xor(bv, off);
                    const int    oi = __shfl_xor(bi, off);
                    if (ov > bv || (ov == bv && oi < bi)) { bv = ov; bi = oi; }
                }
                const double bp = exp(bv - m);
                tsum += bp;
                if (lane == r)  { myp = bp; myi = bi; }
                if (lane == bi) pv = -1.0e300;
            }
            if (lane < 8) {
                out_idx[(size_t)t * 8 + lane] = (float)myi;
                out_w[(size_t)t * 8 + lane]   = (float)(myp / tsum);
            }
        }
    }
}

// ---------------------------------------------------------------------------
// Kernel 4: aux loss finalize. 1 block, 256 threads (4 slices x 64 experts).
// ---------------------------------------------------------------------------
__global__ __launch_bounds__(256) void k_aux(const float* __restrict__ expsum, int nb,
                                             float* __restrict__ out_aux) {
    __shared__ float l[4][64];
    const int lane  = threadIdx.x & 63;
    const int slice = threadIdx.x >> 6;
    float s = 0.f;
    for (int b = slice; b < nb; b += 4) s += expsum[(size_t)b * 64 + lane];
    l[slice][lane] = s;
    __syncthreads();
    if (threadIdx.x < 64) {
        const float tot = l[0][lane] + l[1][lane] + l[2][lane] + l[3][lane];
        const float avg = tot * (1.f / (float)T_TOKENS);
        float v = avg * avg;
#pragma unroll
        for (int off = 32; off; off >>= 1) v += __shfl_xor(v, off);
        if (lane == 0) out_aux[0] = (float)N_EXP * 0.001f * v;
    }
}

extern "C" void kernel_launch(void* const* d_in, const int* in_sizes, int n_in,
                              void* d_out, int out_size, void* d_ws, size_t ws_size,
                              hipStream_t stream) {
    const float* h = (const float*)d_in[0];   // [8192,4096]
    const float* w = (const float*)d_in[1];   // [64,4096]
    float* out      = (float*)d_out;
    float* out_idx  = out;                    // 65536 (indices as float)
    float* out_w    = out + 65536;            // 65536
    float* out_aux  = out + 131072;           // 1

    const size_t part_elems = (size_t)T_TOKENS * N_EXP;
    const int NB2 = 512;
    int KS = 16;                              // 512 blocks = 2/CU, 32 MB part
    while (KS > 1 &&
           ((size_t)KS * part_elems * 4 + (size_t)NB2 * 64 * 4 +
            4 + (size_t)T_TOKENS * 4) > ws_size)
        KS >>= 1;

    float* part     = (float*)d_ws;
    float* expsum   = part + (size_t)KS * part_elems;
    int*   flag_cnt = (int*)(expsum + (size_t)NB2 * 64);
    int*   flag_list= flag_cnt + 1;

    hipMemsetAsync(flag_cnt, 0, sizeof(int), stream);

    dim3 g1(T_TOKENS / BT, KS);
    k_gemm<<<g1, 256, 0, stream>>>(h, w, part, D_MODEL / KS);
    k_router<<<NB2, 256, 0, stream>>>(part, KS, out_idx, out_w, expsum,
                                      flag_cnt, flag_list);
    k_repair<<<512, 256, 0, stream>>>(h, w, flag_cnt, flag_list, out_idx, out_w);
    k_aux<<<1, 256, 0, stream>>>(expsum, NB2, out_aux);
}

// Round 9
// 169.664 us; speedup vs baseline: 1.9428x; 1.0015x over previous
//
#include <hip/hip_runtime.h>

#define T_TOKENS 8192
#define D_MODEL  4096
#define N_EXP    64
#define BT       256          // tokens per gemm block
#define TAU      4e-6f        // gap threshold for f64 repair (~285 sigma of f32 err)

#define GLB(p)  ((const __attribute__((address_space(1))) void*)(p))
#define LDSP(p) ((__attribute__((address_space(3))) void*)(p))

// ---------------------------------------------------------------------------
// Kernel 1: f32 partial GEMM, 2-phase LDS double-buffer (R8) + register
// double-buffered compute pipeline (NEW): reads for u-step n+1 are issued
// while u-step n's FMAs run, breaking the read-burst/FMA-burst convoy that
// capped VALUBusy at 41%. Named reg buffers A/B, fully static indexing.
// ---------------------------------------------------------------------------
__global__ __launch_bounds__(256) void k_gemm(const float* __restrict__ h,
                                              const float* __restrict__ w,
                                              float* __restrict__ part,
                                              int ks_len) {
    __shared__ float lh[2][BT][32];     // 64 KB
    __shared__ float lw[2][N_EXP][32];  // 16 KB  => 80 KB total, 2 blocks/CU
    const int tid  = threadIdx.x;
    const int wv   = tid >> 6;       // wave 0..3
    const int lane = tid & 63;
    const int T0   = blockIdx.x * BT;
    const int k0   = blockIdx.y * ks_len;

    const int tloc = wv * 64 + (lane & 7) * 8;  // 8 consecutive tokens
    const int eloc = (lane >> 3) * 8;           // 8 consecutive experts
    const int ko   = (lane & 15) * 2;           // even k-stagger offset

    // per-thread global staging bases (advance by it*32 floats per tile)
    const float* ghb = h + (size_t)(T0 + wv * 64 + (lane >> 3)) * D_MODEL
                         + k0 + (lane & 7) * 4;
    const float* gwb = w + (size_t)(wv * 16 + (lane >> 3)) * D_MODEL
                         + k0 + (lane & 7) * 4;

    float acc[8][8];
#pragma unroll
    for (int i = 0; i < 8; ++i)
#pragma unroll
        for (int j = 0; j < 8; ++j) acc[i][j] = 0.f;

    auto stage = [&](int b, int it) {
#pragma unroll
        for (int q = 0; q < 8; ++q)
            __builtin_amdgcn_global_load_lds(
                GLB(ghb + it * 32 + (size_t)q * 8 * D_MODEL),
                LDSP(&lh[b][wv * 64 + q * 8][0]), 16, 0, 0);
#pragma unroll
        for (int q = 0; q < 2; ++q)
            __builtin_amdgcn_global_load_lds(
                GLB(gwb + it * 32 + (size_t)q * 8 * D_MODEL),
                LDSP(&lw[b][wv * 16 + q * 8][0]), 16, 0, 0);
    };

    float2 ha[8], wa[8], hb[8], wb[8];  // reg double-buffer (A/B, static)

    auto loadu = [&](int b, int u, float2 (&hv)[8], float2 (&wvv)[8]) {
        const int kk = (2 * u + ko) & 31;       // staggered k (even)
#pragma unroll
        for (int i = 0; i < 8; ++i)
            hv[i] = *reinterpret_cast<const float2*>(&lh[b][tloc + i][kk]);
#pragma unroll
        for (int j = 0; j < 8; ++j)
            wvv[j] = *reinterpret_cast<const float2*>(&lw[b][eloc + j][kk]);
    };
    auto fmau = [&](const float2 (&hv)[8], const float2 (&wvv)[8]) {
#pragma unroll
        for (int i = 0; i < 8; ++i)
#pragma unroll
            for (int j = 0; j < 8; ++j) {
                acc[i][j] = fmaf(hv[i].x, wvv[j].x, acc[i][j]);
                acc[i][j] = fmaf(hv[i].y, wvv[j].y, acc[i][j]);
            }
    };

    const int iters = ks_len >> 5;      // 8 tiles at KS=16
    stage(0, 0);
    __syncthreads();                    // prologue drain (exposed once)
    for (int it = 0; it < iters; ++it) {
        const int b = it & 1;
        if (it + 1 < iters) stage(b ^ 1, it + 1);   // lands during compute
        loadu(b, 0, ha, wa);
#pragma unroll
        for (int u = 0; u < 16; u += 2) {
            loadu(b, u + 1, hb, wb);                // issue during fmau(A)
            fmau(ha, wa);
            if (u + 2 < 16) loadu(b, u + 2, ha, wa); // issue during fmau(B)
            fmau(hb, wb);
        }
        __syncthreads();   // next-buf writes visible; cur readers done
    }

    float* base = part + ((size_t)blockIdx.y * T_TOKENS + T0) * N_EXP;
#pragma unroll
    for (int i = 0; i < 8; ++i) {
        const int t = tloc + i;
        const float4 o0 = make_float4(acc[i][0], acc[i][1], acc[i][2], acc[i][3]);
        const float4 o1 = make_float4(acc[i][4], acc[i][5], acc[i][6], acc[i][7]);
        *reinterpret_cast<float4*>(&base[(size_t)t * N_EXP + eloc])     = o0;
        *reinterpret_cast<float4*>(&base[(size_t)t * N_EXP + eloc + 4]) = o1;
    }
}

// ---------------------------------------------------------------------------
// Kernel 2: per-token softmax + top-8 + gap-based tie flagging + aux partials.
// block 256 (4 waves), wave handles 4 tokens, lane = expert. f32 throughout.
// ---------------------------------------------------------------------------
__global__ __launch_bounds__(256) void k_router(const float* __restrict__ part, int KS,
                                                float* __restrict__ out_idx,
                                                float* __restrict__ out_w,
                                                float* __restrict__ expsum,
                                                int* __restrict__ flag_cnt,
                                                int* __restrict__ flag_list) {
    __shared__ float laux[4][64];
    const int lane = threadIdx.x & 63;
    const int wid  = threadIdx.x >> 6;
    float aux_acc = 0.f;
    const int tbase = blockIdx.x * 16 + wid * 4;
    const size_t kstride = (size_t)T_TOKENS * N_EXP;

    for (int tt = 0; tt < 4; ++tt) {
        const int t = tbase + tt;
        const float* pb = part + (size_t)t * N_EXP + lane;
        float a0 = 0.f, a1 = 0.f, a2 = 0.f, a3 = 0.f;
        int ksi = 0;
        for (; ksi + 4 <= KS; ksi += 4) {
            a0 += pb[(size_t)(ksi + 0) * kstride];
            a1 += pb[(size_t)(ksi + 1) * kstride];
            a2 += pb[(size_t)(ksi + 2) * kstride];
            a3 += pb[(size_t)(ksi + 3) * kstride];
        }
        for (; ksi < KS; ++ksi) a0 += pb[(size_t)ksi * kstride];
        const float lg = (a0 + a1) + (a2 + a3);

        float m = lg;
#pragma unroll
        for (int off = 32; off; off >>= 1) m = fmaxf(m, __shfl_xor(m, off));
        const float p = __expf(lg - m);
        float s = p;
#pragma unroll
        for (int off = 32; off; off >>= 1) s += __shfl_xor(s, off);
        const float inv_s = 1.f / s;
        aux_acc += p * inv_s;

        // top-9 rounds: select top-8, measure all 9 adjacent gaps
        float pv = lg; int pi = lane;
        float myp = 0.f; int myi = 0; float tsum = 0.f, prev = 0.f;
        bool flg = false;
#pragma unroll
        for (int r = 0; r < 9; ++r) {
            float bv = pv; int bi = pi;
#pragma unroll
            for (int off = 32; off; off >>= 1) {
                const float ov = __shfl_xor(bv, off);
                const int   oi = __shfl_xor(bi, off);
                if (ov > bv || (ov == bv && oi < bi)) { bv = ov; bi = oi; }
            }
            if (r > 0) flg = flg || (prev - bv < TAU);
            prev = bv;
            if (r < 8) {
                const float bp = __expf(bv - m) * inv_s;
                tsum += bp;
                if (lane == r)  { myp = bp; myi = bi; }
                if (lane == bi) pv = -1e30f;
            }
        }
        if (lane < 8) {
            out_idx[(size_t)t * 8 + lane] = (float)myi;
            out_w[(size_t)t * 8 + lane]   = myp / tsum;
        }
        if (lane == 0 && flg) {
            const int pos = atomicAdd(flag_cnt, 1);
            if (pos < T_TOKENS) flag_list[pos] = t;
        }
    }

    laux[wid][lane] = aux_acc;
    __syncthreads();
    if (threadIdx.x < 64)
        expsum[(size_t)blockIdx.x * 64 + threadIdx.x] =
            laux[0][threadIdx.x] + laux[1][threadIdx.x] +
            laux[2][threadIdx.x] + laux[3][threadIdx.x];
}

// ---------------------------------------------------------------------------
// Kernel 3: f64 repair, one block per flagged token. lane = expert, wave = k
// chunk. Inner loop unrolled 8x (16 loads in flight, 8 independent f64 acc).
// ---------------------------------------------------------------------------
__global__ __launch_bounds__(256) void k_repair(const float* __restrict__ h,
                                                const float* __restrict__ w,
                                                const int* __restrict__ flag_cnt,
                                                const int* __restrict__ flag_list,
                                                float* __restrict__ out_idx,
                                                float* __restrict__ out_w) {
    __shared__ float  sh[D_MODEL];   // 16 KB
    __shared__ double sp[4][64];     //  2 KB
    const int tid  = threadIdx.x;
    const int lane = tid & 63;
    const int c    = tid >> 6;       // k-chunk = wave id
    const int n = min(*flag_cnt, T_TOKENS);

    for (int i = blockIdx.x; i < n; i += gridDim.x) {
        const int t = flag_list[i];
        __syncthreads();   // previous iteration's readers done
#pragma unroll
        for (int q = 0; q < 4; ++q) {
            const int o = (q * 256 + tid) * 4;
            *reinterpret_cast<float4*>(&sh[o]) =
                *reinterpret_cast<const float4*>(&h[(size_t)t * D_MODEL + o]);
        }
        __syncthreads();

        const float* wp = &w[(size_t)lane * D_MODEL + c * 1024];
        const float* hp = &sh[c * 1024];
        double acc[8] = {0, 0, 0, 0, 0, 0, 0, 0};
        for (int q = 0; q < 32; ++q) {          // 32 chunks x 8 float4
            float4 wv8[8], hv8[8];
#pragma unroll
            for (int u = 0; u < 8; ++u) {
                wv8[u] = *reinterpret_cast<const float4*>(&wp[(q * 8 + u) * 4]);
                hv8[u] = *reinterpret_cast<const float4*>(&hp[(q * 8 + u) * 4]);
            }
#pragma unroll
            for (int u = 0; u < 8; ++u) {
                acc[u] = fma((double)hv8[u].x, (double)wv8[u].x, acc[u]);
                acc[u] = fma((double)hv8[u].y, (double)wv8[u].y, acc[u]);
                acc[u] = fma((double)hv8[u].z, (double)wv8[u].z, acc[u]);
                acc[u] = fma((double)hv8[u].w, (double)wv8[u].w, acc[u]);
            }
        }
        sp[c][lane] = (((acc[0] + acc[1]) + (acc[2] + acc[3])) +
                       ((acc[4] + acc[5]) + (acc[6] + acc[7])));
        __syncthreads();

        if (tid < 64) {
            const double mylg = ((sp[0][lane] + sp[1][lane]) +
                                 (sp[2][lane] + sp[3][lane]));
            double m = mylg;
#pragma unroll
            for (int off = 32; off; off >>= 1) m = fmax(m, __shfl_xor(m, off));
            double pv = mylg; int pi = lane;
            double myp = 0.0; int myi = 0; double tsum = 0.0;
#pragma unroll
            for (int r = 0; r < 8; ++r) {
                double bv = pv; int bi = pi;
#pragma unroll
                for (int off = 32; off; off >>= 1) {
                    const double ov = __shfl_xor(bv, off);
                    const int    oi = __shfl_xor(bi, off);
                    if (ov > bv || (ov == bv && oi < bi)) { bv = ov; bi = oi; }
                }
                const double bp = exp(bv - m);
                tsum += bp;
                if (lane == r)  { myp = bp; myi = bi; }
                if (lane == bi) pv = -1.0e300;
            }
            if (lane < 8) {
                out_idx[(size_t)t * 8 + lane] = (float)myi;
                out_w[(size_t)t * 8 + lane]   = (float)(myp / tsum);
            }
        }
    }
}

// ---------------------------------------------------------------------------
// Kernel 4: aux loss finalize. 1 block, 256 threads (4 slices x 64 experts).
// ---------------------------------------------------------------------------
__global__ __launch_bounds__(256) void k_aux(const float* __restrict__ expsum, int nb,
                                             float* __restrict__ out_aux) {
    __shared__ float l[4][64];
    const int lane  = threadIdx.x & 63;
    const int slice = threadIdx.x >> 6;
    float s = 0.f;
    for (int b = slice; b < nb; b += 4) s += expsum[(size_t)b * 64 + lane];
    l[slice][lane] = s;
    __syncthreads();
    if (threadIdx.x < 64) {
        const float tot = l[0][lane] + l[1][lane] + l[2][lane] + l[3][lane];
        const float avg = tot * (1.f / (float)T_TOKENS);
        float v = avg * avg;
#pragma unroll
        for (int off = 32; off; off >>= 1) v += __shfl_xor(v, off);
        if (lane == 0) out_aux[0] = (float)N_EXP * 0.001f * v;
    }
}

extern "C" void kernel_launch(void* const* d_in, const int* in_sizes, int n_in,
                              void* d_out, int out_size, void* d_ws, size_t ws_size,
                              hipStream_t stream) {
    const float* h = (const float*)d_in[0];   // [8192,4096]
    const float* w = (const float*)d_in[1];   // [64,4096]
    float* out      = (float*)d_out;
    float* out_idx  = out;                    // 65536 (indices as float)
    float* out_w    = out + 65536;            // 65536
    float* out_aux  = out + 131072;           // 1

    const size_t part_elems = (size_t)T_TOKENS * N_EXP;
    const int NB2 = 512;
    int KS = 16;                              // 512 blocks = 2/CU, 32 MB part
    while (KS > 1 &&
           ((size_t)KS * part_elems * 4 + (size_t)NB2 * 64 * 4 +
            4 + (size_t)T_TOKENS * 4) > ws_size)
        KS >>= 1;

    float* part     = (float*)d_ws;
    float* expsum   = part + (size_t)KS * part_elems;
    int*   flag_cnt = (int*)(expsum + (size_t)NB2 * 64);
    int*   flag_list= flag_cnt + 1;

    hipMemsetAsync(flag_cnt, 0, sizeof(int), stream);

    dim3 g1(T_TOKENS / BT, KS);
    k_gemm<<<g1, 256, 0, stream>>>(h, w, part, D_MODEL / KS);
    k_router<<<NB2, 256, 0, stream>>>(part, KS, out_idx, out_w, expsum,
                                      flag_cnt, flag_list);
    k_repair<<<512, 256, 0, stream>>>(h, w, flag_cnt, flag_list, out_idx, out_w);
    k_aux<<<1, 256, 0, stream>>>(expsum, NB2, out_aux);
}